// Round 3
// baseline (71.896 us; speedup 1.0000x reference)
//
#include <hip/hip_runtime.h>
#include <hip/hip_bf16.h>

typedef __attribute__((ext_vector_type(8))) short bf16x8;
typedef __attribute__((ext_vector_type(4))) float f32x4;

static __device__ __forceinline__ unsigned short f2bf(float f) {
    unsigned int u = __float_as_uint(f);
    unsigned int rnd = 0x7FFFu + ((u >> 16) & 1u);
    return (unsigned short)((u + rnd) >> 16);
}

// pack two f32 -> 2xbf16 (RNE) using v_cvt_pk_bf16_f32
static __device__ __forceinline__ bf16x8 cvt8(float4 u, float4 v) {
    union { bf16x8 r; __hip_bfloat162 h[4]; } o;
    o.h[0] = __float22bfloat162_rn(float2{u.x, u.y});
    o.h[1] = __float22bfloat162_rn(float2{u.z, u.w});
    o.h[2] = __float22bfloat162_rn(float2{v.x, v.y});
    o.h[3] = __float22bfloat162_rn(float2{v.z, v.w});
    return o.r;
}

// ---------------- Kernel 1: hypernetwork hw = hyper@W1+b1, bias = hyper@Wb+bb
// Parallel version: 32 outputs per block, 8-way d-split per output, LDS reduce.
// Thread layout tid = p*32 + jj so each load instruction is 128B-contiguous.
__global__ __launch_bounds__(256)
void hypernet_kernel(const float* __restrict__ hyper,   // (8,256)
                     const float* __restrict__ W1,      // (256,4096)
                     const float* __restrict__ b1,      // (4096)
                     const float* __restrict__ Wb,      // (256,64)
                     const float* __restrict__ bb,      // (64)
                     float* __restrict__ hw,            // ws: 8*4096
                     float* __restrict__ bias)          // ws: 8*64
{
    __shared__ float red[256];
    const int tid = threadIdx.x;
    const int p   = tid >> 5;          // 0..7  (d-range)
    const int jj  = tid & 31;          // 0..31 (output within block)
    const int o0  = blockIdx.x * 32;
    const int o   = o0 + jj;

    float acc = 0.f;
    if (o0 < 8 * 4096) {               // hw part (uniform per block)
        int h = o >> 12, j = o & 4095;
        const float* hr = hyper + (h << 8);
        #pragma unroll
        for (int i = 0; i < 32; ++i) {
            int d = (p << 5) + i;
            acc += hr[d] * W1[d * 4096 + j];
        }
    } else {                           // bias part
        int t = o - 8 * 4096;          // 0..511
        int h = t >> 6, s = t & 63;
        const float* hr = hyper + (h << 8);
        #pragma unroll
        for (int i = 0; i < 32; ++i) {
            int d = (p << 5) + i;
            acc += hr[d] * Wb[d * 64 + s];
        }
    }
    red[tid] = acc;
    __syncthreads();
    if (p == 0) {
        float sum = red[jj]       + red[32 + jj]  + red[64 + jj]  + red[96 + jj]
                  + red[128 + jj] + red[160 + jj] + red[192 + jj] + red[224 + jj];
        if (o0 < 8 * 4096) hw[o] = sum + b1[o & 4095];
        else {
            int t = o - 8 * 4096;
            bias[t] = sum + bb[t & 63];
        }
    }
}

// ---------------- Kernel 2: W[h] = down@up, packed directly into MFMA
// B-fragment order for v_mfma_f32_16x16x32_bf16 (validated in round 1).
__global__ void pack_kernel(const float* __restrict__ hw,          // 8*4096
                            unsigned short* __restrict__ packed)   // 32768 bf16
{
    int p = blockIdx.x * blockDim.x + threadIdx.x;  // 0..32767
    int b   = p & 7;
    int l   = (p >> 3) & 63;
    int kap = (p >> 9) & 1;
    int n   = p >> 10;                              // 0..31
    int k   = kap * 32 + ((l >> 4) << 3) + b;       // 0..63 (= target feature d)
    int col = (n << 4) + (l & 15);                  // 0..511
    int h = col >> 6, s = col & 63;
    const float* hwh = hw + h * 4096;
    float acc = 0.f;
    #pragma unroll
    for (int r = 0; r < 32; ++r)
        acc += hwh[k * 32 + r] * hwh[2048 + r * 64 + s];
    packed[p] = f2bf(acc);
}

// ---------------- Kernel 3: main — wave-independent streaming GEMM + epilogue
// Block b owns rows [b*16*TPW, ...). Wave w owns output cols [w*16, w*16+16)
// and loops over TPW row-tiles of 16 with distance-1 X prefetch. No LDS, no sync.
#define TPW 4   // row-tiles per wave

__global__ __launch_bounds__(256, 4)
void main_kernel(const float* __restrict__ X,       // (M,64)
                 const float* __restrict__ Mask,    // (M,8)
                 const unsigned short* __restrict__ packedB,
                 const float* __restrict__ bias,    // (8,64)
                 float* __restrict__ Out)           // (M,64)
{
    const int tid  = threadIdx.x;
    const int lane = tid & 63;
    const int w    = tid >> 6;          // wave id 0..3 -> output col tile
    const int c    = lane & 15;         // A row-within-tile / D col-within-tile
    const int g    = lane >> 4;         // k-group / D row-group
    const int rowBase = blockIdx.x * (16 * TPW);
    const int s = (w << 4) + c;         // output column 0..63

    // ---- B fragments for this wave (reused over all TPW tiles)
    bf16x8 Bf[8][2];
    #pragma unroll
    for (int h = 0; h < 8; ++h) {
        const unsigned short* pb = packedB + ((((h * 4 + w) * 2) * 64) + lane) * 8;
        Bf[h][0] = *(const bf16x8*)pb;
        Bf[h][1] = *(const bf16x8*)(pb + 512);
    }

    // ---- bias for this lane's output column
    float biasr[8];
    #pragma unroll
    for (int h = 0; h < 8; ++h) biasr[h] = bias[h * 64 + s];

    // lane reads X row (rowBase + t*16 + c), cols [g*8,g*8+8) and [32+g*8, ...)
    const float* xrow = X + (rowBase + c) * 64 + (g << 3);
    const float* mrow = Mask + (rowBase + (g << 2)) * 8;

    // ---- prologue: prefetch tile 0
    float4 px0 = *(const float4*)(xrow);
    float4 px1 = *(const float4*)(xrow + 4);
    float4 px2 = *(const float4*)(xrow + 32);
    float4 px3 = *(const float4*)(xrow + 36);

    #pragma unroll 2
    for (int t = 0; t < TPW; ++t) {
        float4 cx0 = px0, cx1 = px1, cx2 = px2, cx3 = px3;

        // mask for tile t: 4 rows x 8 f32, contiguous 128B per lane-group
        const float* mp = mrow + t * 128;
        float4 m0 = *(const float4*)(mp);      float4 m1 = *(const float4*)(mp + 4);
        float4 m2 = *(const float4*)(mp + 8);  float4 m3 = *(const float4*)(mp + 12);
        float4 m4 = *(const float4*)(mp + 16); float4 m5 = *(const float4*)(mp + 20);
        float4 m6 = *(const float4*)(mp + 24); float4 m7 = *(const float4*)(mp + 28);

        // prefetch X for tile t+1
        if (t + 1 < TPW) {
            const float* xp = xrow + (t + 1) * 1024;
            px0 = *(const float4*)(xp);
            px1 = *(const float4*)(xp + 4);
            px2 = *(const float4*)(xp + 32);
            px3 = *(const float4*)(xp + 36);
        }

        bf16x8 a0 = cvt8(cx0, cx1);     // cols [g*8, g*8+8)
        bf16x8 a1 = cvt8(cx2, cx3);     // cols [32+g*8, 32+g*8+8)

        f32x4 acc[8];
        #pragma unroll
        for (int h = 0; h < 8; ++h) acc[h] = (f32x4)(0.f);
        #pragma unroll
        for (int h = 0; h < 8; ++h) {
            acc[h] = __builtin_amdgcn_mfma_f32_16x16x32_bf16(a0, Bf[h][0], acc[h], 0, 0, 0);
            acc[h] = __builtin_amdgcn_mfma_f32_16x16x32_bf16(a1, Bf[h][1], acc[h], 0, 0, 0);
        }

        // epilogue: out[row,s] = sum_h m[row,h] * (Z + bias)
        #pragma unroll
        for (int i = 0; i < 4; ++i) {
            const float4 ml = (i == 0) ? m0 : (i == 1) ? m2 : (i == 2) ? m4 : m6;
            const float4 mh = (i == 0) ? m1 : (i == 1) ? m3 : (i == 2) ? m5 : m7;
            float o = ml.x * (acc[0][i] + biasr[0]);
            o = fmaf(ml.y, acc[1][i] + biasr[1], o);
            o = fmaf(ml.z, acc[2][i] + biasr[2], o);
            o = fmaf(ml.w, acc[3][i] + biasr[3], o);
            o = fmaf(mh.x, acc[4][i] + biasr[4], o);
            o = fmaf(mh.y, acc[5][i] + biasr[5], o);
            o = fmaf(mh.z, acc[6][i] + biasr[6], o);
            o = fmaf(mh.w, acc[7][i] + biasr[7], o);
            Out[(rowBase + t * 16 + (g << 2) + i) * 64 + s] = o;
        }
    }
}

extern "C" void kernel_launch(void* const* d_in, const int* in_sizes, int n_in,
                              void* d_out, int out_size, void* d_ws, size_t ws_size,
                              hipStream_t stream) {
    const float* target = (const float*)d_in[0];   // (B,L,64)
    const float* hyper  = (const float*)d_in[1];   // (8,256)
    const float* mask   = (const float*)d_in[2];   // (B,L,8)
    const float* W1     = (const float*)d_in[3];   // (256,4096)
    const float* b1     = (const float*)d_in[4];   // (4096)
    const float* Wb     = (const float*)d_in[5];   // (256,64)
    const float* bb     = (const float*)d_in[6];   // (64)
    float* out = (float*)d_out;

    float* hw   = (float*)d_ws;                         // 32768 f32
    float* bias = hw + 8 * 4096;                        // 512 f32
    unsigned short* packed = (unsigned short*)(bias + 512); // 32768 bf16

    const int M = in_sizes[0] / 64;                     // 131072 rows

    // 32 outputs/block over (8*4096 + 8*64) outputs = 1040 blocks
    hipLaunchKernelGGL(hypernet_kernel, dim3((8 * 4096 + 8 * 64) / 32), dim3(256),
                       0, stream, hyper, W1, b1, Wb, bb, hw, bias);
    hipLaunchKernelGGL(pack_kernel, dim3(32768 / 256), dim3(256), 0, stream, hw, packed);
    hipLaunchKernelGGL(main_kernel, dim3(M / (16 * TPW)), dim3(256), 0, stream,
                       target, mask, packed, bias, out);
}

// Round 4
// 36.792 us; speedup vs baseline: 1.9541x; 1.9541x over previous
//
#include <hip/hip_runtime.h>
#include <hip/hip_bf16.h>

typedef __attribute__((ext_vector_type(8))) short bf16x8;
typedef __attribute__((ext_vector_type(4))) float f32x4;

static __device__ __forceinline__ unsigned short f2bf(float f) {
    unsigned int u = __float_as_uint(f);
    unsigned int rnd = 0x7FFFu + ((u >> 16) & 1u);
    return (unsigned short)((u + rnd) >> 16);
}

// pack two f32 -> 2xbf16 (RNE) using v_cvt_pk_bf16_f32
static __device__ __forceinline__ bf16x8 cvt8(float4 u, float4 v) {
    union { bf16x8 r; __hip_bfloat162 h[4]; } o;
    o.h[0] = __float22bfloat162_rn(float2{u.x, u.y});
    o.h[1] = __float22bfloat162_rn(float2{u.z, u.w});
    o.h[2] = __float22bfloat162_rn(float2{v.x, v.y});
    o.h[3] = __float22bfloat162_rn(float2{v.z, v.w});
    return o.r;
}

// ---------------- Kernel 1: hypernetwork hw = hyper@W1+b1, bias = hyper@Wb+bb
// 32 outputs per block, 8-way d-split per output, LDS reduce.
__global__ __launch_bounds__(256)
void hypernet_kernel(const float* __restrict__ hyper,   // (8,256)
                     const float* __restrict__ W1,      // (256,4096)
                     const float* __restrict__ b1,      // (4096)
                     const float* __restrict__ Wb,      // (256,64)
                     const float* __restrict__ bb,      // (64)
                     float* __restrict__ hw,            // ws: 8*4096
                     float* __restrict__ bias)          // ws: 8*64
{
    __shared__ float red[256];
    const int tid = threadIdx.x;
    const int p   = tid >> 5;          // 0..7  (d-range)
    const int jj  = tid & 31;          // 0..31 (output within block)
    const int o0  = blockIdx.x * 32;
    const int o   = o0 + jj;

    float acc = 0.f;
    if (o0 < 8 * 4096) {               // hw part (uniform per block)
        int h = o >> 12, j = o & 4095;
        const float* hr = hyper + (h << 8);
        #pragma unroll
        for (int i = 0; i < 32; ++i) {
            int d = (p << 5) + i;
            acc += hr[d] * W1[d * 4096 + j];
        }
    } else {                           // bias part
        int t = o - 8 * 4096;          // 0..511
        int h = t >> 6, s = t & 63;
        const float* hr = hyper + (h << 8);
        #pragma unroll
        for (int i = 0; i < 32; ++i) {
            int d = (p << 5) + i;
            acc += hr[d] * Wb[d * 64 + s];
        }
    }
    red[tid] = acc;
    __syncthreads();
    if (p == 0) {
        float sum = red[jj]       + red[32 + jj]  + red[64 + jj]  + red[96 + jj]
                  + red[128 + jj] + red[160 + jj] + red[192 + jj] + red[224 + jj];
        if (o0 < 8 * 4096) hw[o] = sum + b1[o & 4095];
        else {
            int t = o - 8 * 4096;
            bias[t] = sum + bb[t & 63];
        }
    }
}

// ---------------- Kernel 2: W[h] = down@up, packed directly into MFMA
// B-fragment order for v_mfma_f32_16x16x32_bf16 (validated in round 1).
__global__ void pack_kernel(const float* __restrict__ hw,          // 8*4096
                            unsigned short* __restrict__ packed)   // 32768 bf16
{
    int p = blockIdx.x * blockDim.x + threadIdx.x;  // 0..32767
    int b   = p & 7;
    int l   = (p >> 3) & 63;
    int kap = (p >> 9) & 1;
    int n   = p >> 10;                              // 0..31
    int k   = kap * 32 + ((l >> 4) << 3) + b;       // 0..63 (= target feature d)
    int col = (n << 4) + (l & 15);                  // 0..511
    int h = col >> 6, s = col & 63;
    const float* hwh = hw + h * 4096;
    float acc = 0.f;
    #pragma unroll
    for (int r = 0; r < 32; ++r)
        acc += hwh[k * 32 + r] * hwh[2048 + r * 64 + s];
    packed[p] = f2bf(acc);
}

// ---------------- Kernel 3: main — streaming GEMM + masked-H epilogue.
// Masks live in LDS (broadcast reads) to cut ~32 VGPRs vs round 2, so the
// kernel fits 3 waves/SIMD (launch_bounds cap 170) WITHOUT spilling.
// One __syncthreads at kernel start only; waves run tiles independently.
#define TPW 4   // row-tiles per wave; block covers 64 rows

__global__ __launch_bounds__(256, 3)
void main_kernel(const float* __restrict__ X,       // (M,64)
                 const float* __restrict__ Mask,    // (M,8)
                 const unsigned short* __restrict__ packedB,
                 const float* __restrict__ bias,    // (8,64)
                 float* __restrict__ Out)           // (M,64)
{
    __shared__ float sM[16 * TPW * 8];  // 2 KB: 64 rows x 8 masks

    const int tid  = threadIdx.x;
    const int lane = tid & 63;
    const int w    = tid >> 6;          // wave id 0..3 -> output col tile
    const int c    = lane & 15;         // A row-within-tile / D col-within-tile
    const int g    = lane >> 4;         // k-group / D row-group
    const int rowBase = blockIdx.x * (16 * TPW);
    const int s = (w << 4) + c;         // output column 0..63

    // ---- stage mask tile to LDS: 512 floats = 256 float2
    {
        const float2* Mv = (const float2*)(Mask + (long)rowBase * 8);
        ((float2*)sM)[tid] = Mv[tid];
    }

    // ---- B fragments for this wave (L2-hot 64KB buffer)
    bf16x8 Bf[8][2];
    #pragma unroll
    for (int h = 0; h < 8; ++h) {
        const unsigned short* pb = packedB + ((((h * 4 + w) * 2) * 64) + lane) * 8;
        Bf[h][0] = *(const bf16x8*)pb;
        Bf[h][1] = *(const bf16x8*)(pb + 512);
    }

    // ---- bias for this lane's output column
    float biasr[8];
    #pragma unroll
    for (int h = 0; h < 8; ++h) biasr[h] = bias[h * 64 + s];

    // lane reads X row (rowBase + t*16 + c), cols [g*8,g*8+8) and [32+g*8, ...)
    const float* xrow = X + (long)(rowBase + c) * 64 + (g << 3);

    // ---- prologue: prefetch tile 0
    float4 px0 = *(const float4*)(xrow);
    float4 px1 = *(const float4*)(xrow + 4);
    float4 px2 = *(const float4*)(xrow + 32);
    float4 px3 = *(const float4*)(xrow + 36);

    __syncthreads();

    #pragma unroll 2
    for (int t = 0; t < TPW; ++t) {
        float4 cx0 = px0, cx1 = px1, cx2 = px2, cx3 = px3;

        // prefetch X for tile t+1
        if (t + 1 < TPW) {
            const float* xp = xrow + (t + 1) * 1024;
            px0 = *(const float4*)(xp);
            px1 = *(const float4*)(xp + 4);
            px2 = *(const float4*)(xp + 32);
            px3 = *(const float4*)(xp + 36);
        }

        bf16x8 a0 = cvt8(cx0, cx1);     // cols [g*8, g*8+8)
        bf16x8 a1 = cvt8(cx2, cx3);     // cols [32+g*8, 32+g*8+8)

        f32x4 acc[8];
        #pragma unroll
        for (int h = 0; h < 8; ++h) acc[h] = (f32x4)(0.f);
        #pragma unroll
        for (int h = 0; h < 8; ++h) {
            acc[h] = __builtin_amdgcn_mfma_f32_16x16x32_bf16(a0, Bf[h][0], acc[h], 0, 0, 0);
            acc[h] = __builtin_amdgcn_mfma_f32_16x16x32_bf16(a1, Bf[h][1], acc[h], 0, 0, 0);
        }

        // epilogue: out[row,s] = sum_h m[row,h] * (Z + bias)
        // masks via LDS broadcast (16 lanes share each address)
        #pragma unroll
        for (int i = 0; i < 4; ++i) {
            const int r = t * 16 + (g << 2) + i;
            const float4 ml = *(const float4*)(&sM[r * 8]);
            const float4 mh = *(const float4*)(&sM[r * 8 + 4]);
            float o = ml.x * (acc[0][i] + biasr[0]);
            o = fmaf(ml.y, acc[1][i] + biasr[1], o);
            o = fmaf(ml.z, acc[2][i] + biasr[2], o);
            o = fmaf(ml.w, acc[3][i] + biasr[3], o);
            o = fmaf(mh.x, acc[4][i] + biasr[4], o);
            o = fmaf(mh.y, acc[5][i] + biasr[5], o);
            o = fmaf(mh.z, acc[6][i] + biasr[6], o);
            o = fmaf(mh.w, acc[7][i] + biasr[7], o);
            Out[(long)(rowBase + r) * 64 + s] = o;
        }
    }
}

extern "C" void kernel_launch(void* const* d_in, const int* in_sizes, int n_in,
                              void* d_out, int out_size, void* d_ws, size_t ws_size,
                              hipStream_t stream) {
    const float* target = (const float*)d_in[0];   // (B,L,64)
    const float* hyper  = (const float*)d_in[1];   // (8,256)
    const float* mask   = (const float*)d_in[2];   // (B,L,8)
    const float* W1     = (const float*)d_in[3];   // (256,4096)
    const float* b1     = (const float*)d_in[4];   // (4096)
    const float* Wb     = (const float*)d_in[5];   // (256,64)
    const float* bb     = (const float*)d_in[6];   // (64)
    float* out = (float*)d_out;

    float* hw   = (float*)d_ws;                         // 32768 f32
    float* bias = hw + 8 * 4096;                        // 512 f32
    unsigned short* packed = (unsigned short*)(bias + 512); // 32768 bf16

    const int M = in_sizes[0] / 64;                     // 131072 rows

    hipLaunchKernelGGL(hypernet_kernel, dim3((8 * 4096 + 8 * 64) / 32), dim3(256),
                       0, stream, hyper, W1, b1, Wb, bb, hw, bias);
    hipLaunchKernelGGL(pack_kernel, dim3(32768 / 256), dim3(256), 0, stream, hw, packed);
    hipLaunchKernelGGL(main_kernel, dim3(M / (16 * TPW)), dim3(256), 0, stream,
                       target, mask, packed, bias, out);
}